// Round 1
// baseline (349.890 us; speedup 1.0000x reference)
//
#include <hip/hip_runtime.h>
#include <math.h>

#define NHEAD 8
#define DIM   16
#define EPSF  1e-6f

// ---- solved_sample flag decode, robust to int32 / float32 / byte-bool marshalling.
__device__ __forceinline__ bool solved_flag(const void* p, int i) {
    const unsigned int* u = (const unsigned int*)p;
    unsigned int v0 = u[0];
    if (v0 <= 1u)             return u[i] != 0u;                   // int32 0/1
    if (v0 == 0x3F800000u)    return ((const float*)p)[i] != 0.0f; // float32
    return ((const unsigned char*)p)[i] != 0;                      // 1-byte bools
}

__device__ __forceinline__ float fm(float x) {           // elu(x)+1
    return x > 0.f ? x + 1.f : expf(x);
}

// ---- elementwise feature map for K (precompute so the gather loop avoids exp)
__global__ void featmap_k(const float4* __restrict__ in, float4* __restrict__ outp, int n4) {
    int i = blockIdx.x * blockDim.x + threadIdx.x;
    if (i < n4) {
        float4 x = in[i];
        x.x = fm(x.x); x.y = fm(x.y); x.z = fm(x.z); x.w = fm(x.w);
        outp[i] = x;
    }
}

// ---- fundamental matrix F per sample: F = inv(K1s)^T * (skew(t)*R) * inv(K0s)
__device__ void inv3d(const double* M, double* inv) {
    double det = M[0]*(M[4]*M[8]-M[5]*M[7]) - M[1]*(M[3]*M[8]-M[5]*M[6]) + M[2]*(M[3]*M[7]-M[4]*M[6]);
    double id = 1.0 / det;
    inv[0] =  (M[4]*M[8]-M[5]*M[7])*id;
    inv[1] = -(M[1]*M[8]-M[2]*M[7])*id;
    inv[2] =  (M[1]*M[5]-M[2]*M[4])*id;
    inv[3] = -(M[3]*M[8]-M[5]*M[6])*id;
    inv[4] =  (M[0]*M[8]-M[2]*M[6])*id;
    inv[5] = -(M[0]*M[5]-M[2]*M[3])*id;
    inv[6] =  (M[3]*M[7]-M[4]*M[6])*id;
    inv[7] = -(M[0]*M[7]-M[1]*M[6])*id;
    inv[8] =  (M[0]*M[4]-M[1]*M[3])*id;
}

__global__ void precompute_F(const float* __restrict__ K0, const float* __restrict__ K1,
                             const float* __restrict__ R,  const float* __restrict__ t,
                             const int* __restrict__ scale_p, float* __restrict__ Fout, int N) {
    int n = blockIdx.x * blockDim.x + threadIdx.x;
    if (n >= N) return;
    float invs = 1.0f / (float)(*scale_p);
    double A[9], B[9];
    for (int i = 0; i < 9; ++i) {
        float a = K0[n*9 + i], b = K1[n*9 + i];
        if (i < 6) { a *= invs; b *= invs; }   // rows 0,1 scaled (matches .at[:, :2, :].mul)
        A[i] = (double)a; B[i] = (double)b;
    }
    double iA[9], iB[9];
    inv3d(A, iA); inv3d(B, iB);
    double tx = t[n*3+0], ty = t[n*3+1], tz = t[n*3+2];
    // skew(t) = [[0,-z,y],[z,0,-x],[-y,x,0]]
    double S[9] = {0.0,-tz,ty, tz,0.0,-tx, -ty,tx,0.0};
    double E[9];
    for (int i = 0; i < 3; ++i)
        for (int j = 0; j < 3; ++j) {
            double s = 0.0;
            for (int k = 0; k < 3; ++k) s += S[i*3+k] * (double)R[n*9 + k*3 + j];
            E[i*3+j] = s;
        }
    // M = E * iA; F = iB^T * M  => F[i][j] = sum_k iB[k*3+i] * M[k*3+j]
    double M[9];
    for (int i = 0; i < 3; ++i)
        for (int j = 0; j < 3; ++j) {
            double s = 0.0;
            for (int k = 0; k < 3; ++k) s += E[i*3+k] * iA[k*3+j];
            M[i*3+j] = s;
        }
    for (int i = 0; i < 3; ++i)
        for (int j = 0; j < 3; ++j) {
            double s = 0.0;
            for (int k = 0; k < 3; ++k) s += iB[k*3+i] * M[k*3+j];
            Fout[n*9 + i*3 + j] = (float)s;
        }
}

// ---- solved-sample attention: one wave per query pixel.
// lane = (h = lane>>3) * 8-lane group; each lane computes the full 16-dot score
// (K loads broadcast within the group) and accumulates 2 output v's.
__launch_bounds__(256)
__global__ void solved_attn(const float* __restrict__ Qr, const float* __restrict__ Kf,
                            const float* __restrict__ Vr, const void* __restrict__ flags,
                            const float* __restrict__ F,  float* __restrict__ outp,
                            const int* __restrict__ h0c_p, const int* __restrict__ w0c_p,
                            int N, int L) {
    int wave = (blockIdx.x * blockDim.x + threadIdx.x) >> 6;
    int lane = threadIdx.x & 63;
    int n = wave / L;
    if (n >= N) return;
    if (!solved_flag(flags, n)) return;
    int s = wave - n * L;
    int W  = *w0c_p;
    int Hc = *h0c_p;
    float px = (float)(s % W);
    float py = (float)(s / W);

    const float* Fn = F + n * 9;
    float a = Fn[0]*px + Fn[1]*py + Fn[2];
    float b = Fn[3]*px + Fn[4]*py + Fn[5];
    float c = Fn[6]*px + Fn[7]*py + Fn[8];
    float nrm = sqrtf(a*a + b*b);
    float mdiv = fmaxf(nrm, 1e-12f);
    a /= mdiv; b /= mdiv; c /= mdiv;
    bool mode = fabsf(b) >= fabsf(a);
    const float hw = 1.5f;

    int h  = lane >> 3;       // head 0..7
    int v0 = (lane & 7) * 2;  // v pair

    // Q fragment (feature-mapped), stays in registers
    const float* qrow = Qr + (((size_t)n * L + s) * NHEAD + h) * DIM;
    float q[16];
    #pragma unroll
    for (int i = 0; i < 16; ++i) q[i] = fm(qrow[i]);

    const float* Kb = Kf + (size_t)n * L * (NHEAD * DIM);
    const float* Vb = Vr + (size_t)n * L * (NHEAD * DIM);

    float num0 = 0.f, num1 = 0.f, den = 0.f;

    float slope, inter;
    int outerN;
    if (mode) {
        float bs = (fabsf(b) < 1e-12f) ? 1e-12f : b;
        slope = -a / bs; inter = -c / bs;
        outerN = W;
    } else {
        float as = (fabsf(a) < 1e-12f) ? 1e-12f : a;
        slope = -b / as; inter = -c / as;
        outerN = Hc;
    }
    int innerMax = mode ? Hc : W;

    for (int o = 0; o < outerN; ++o) {
        float cc = slope * (float)o + inter;   // cy (mode) or cx (!mode)
        float lo = cc - hw, hi = cc + hw;
        int i0 = (int)floorf(lo) + 1;          // smallest integer > lo
        #pragma unroll
        for (int j = 0; j < 3; ++j) {
            int ii = i0 + j;
            if (ii < 0 || ii >= innerMax) continue;
            float fi = (float)ii;
            if (!(fi > lo && fi < hi)) continue;
            int s2 = mode ? (ii * W + o) : (o * W + ii);
            if (s2 == 0) continue;             // reference's gather drops index 0
            const float4* kr = (const float4*)(Kb + (size_t)s2 * (NHEAD*DIM) + h * DIM);
            float4 k0 = kr[0], k1 = kr[1], k2 = kr[2], k3 = kr[3];
            float sc;
            sc  = q[0]*k0.x + q[1]*k0.y + q[2]*k0.z + q[3]*k0.w;
            sc += q[4]*k1.x + q[5]*k1.y + q[6]*k1.z + q[7]*k1.w;
            sc += q[8]*k2.x + q[9]*k2.y + q[10]*k2.z + q[11]*k2.w;
            sc += q[12]*k3.x + q[13]*k3.y + q[14]*k3.z + q[15]*k3.w;
            const float2 vv = *(const float2*)(Vb + (size_t)s2 * (NHEAD*DIM) + h * DIM + v0);
            den  += sc;
            num0 += sc * vv.x;
            num1 += sc * vv.y;
        }
    }
    float r = 1.0f / (den + EPSF);
    size_t ob = (((size_t)n * L + s) * NHEAD + h) * DIM + v0;
    outp[ob]     = num0 * r;
    outp[ob + 1] = num1 * r;
}

// ---- unsolved: KV = sum_s K (x) V   and   Ksum = sum_s K, per (n,h)
__launch_bounds__(256)
__global__ void kv_reduce(const float* __restrict__ Kf, const float* __restrict__ Vr,
                          const void* __restrict__ flags, float* __restrict__ KV,
                          float* __restrict__ Ksum, int N, int L) {
    int n = blockIdx.x >> 3;
    int h = blockIdx.x & 7;
    if (solved_flag(flags, n)) return;
    int t = threadIdx.x;
    int d = t >> 4, v = t & 15;
    __shared__ float Kls[32][16];
    __shared__ float Vls[32][16];
    float acc = 0.f, ks = 0.f;
    int row0 = t >> 4;   // 0..15
    int col  = t & 15;
    for (int sb = 0; sb < L; sb += 32) {
        __syncthreads();
        size_t base0 = (((size_t)n * L + sb + row0)      * NHEAD + h) * DIM + col;
        size_t base1 = (((size_t)n * L + sb + row0 + 16) * NHEAD + h) * DIM + col;
        Kls[row0][col]      = Kf[base0];
        Kls[row0 + 16][col] = Kf[base1];
        Vls[row0][col]      = Vr[base0];
        Vls[row0 + 16][col] = Vr[base1];
        __syncthreads();
        #pragma unroll
        for (int ss = 0; ss < 32; ++ss) {
            float kd = Kls[ss][d];
            acc += kd * Vls[ss][v];
            ks  += kd;
        }
    }
    KV[(((size_t)n * NHEAD + h) * DIM + d) * DIM + v] = acc;
    if (v == 0) Ksum[((size_t)n * NHEAD + h) * DIM + d] = ks;
}

// ---- unsolved: out = Q.KV / (Q.Ksum + eps), one thread per output element
__launch_bounds__(256)
__global__ void unsolved_out(const float* __restrict__ Qr, const float* __restrict__ KV,
                             const float* __restrict__ Ksum, const void* __restrict__ flags,
                             float* __restrict__ outp, int N, int L) {
    long long idx = (long long)blockIdx.x * blockDim.x + threadIdx.x;
    long long tot = (long long)N * L * NHEAD * DIM;
    if (idx >= tot) return;
    int v = (int)(idx & 15);
    int h = (int)((idx >> 4) & 7);
    long long ns = idx >> 7;      // n*L + s
    int n = (int)(ns / L);
    if (solved_flag(flags, n)) return;
    const float* qrow = Qr + (idx & ~(long long)15);
    const float* kv = KV   + ((size_t)n * NHEAD + h) * DIM * DIM;
    const float* kd = Ksum + ((size_t)n * NHEAD + h) * DIM;
    float num = 0.f, den = 0.f;
    #pragma unroll
    for (int d = 0; d < 16; ++d) {
        float qd = fm(qrow[d]);
        num += qd * kv[d * DIM + v];
        den += qd * kd[d];
    }
    outp[idx] = num / (den + EPSF);
}

extern "C" void kernel_launch(void* const* d_in, const int* in_sizes, int n_in,
                              void* d_out, int out_size, void* d_ws, size_t ws_size,
                              hipStream_t stream) {
    const float* Qr   = (const float*)d_in[0];
    const float* Kr   = (const float*)d_in[1];
    const float* Vr   = (const float*)d_in[2];
    const void*  flag = d_in[3];
    const float* K0   = (const float*)d_in[4];
    const float* K1   = (const float*)d_in[5];
    const float* R    = (const float*)d_in[6];
    const float* t    = (const float*)d_in[7];
    const int*   h0c  = (const int*)d_in[8];
    const int*   w0c  = (const int*)d_in[9];
    const int*   scl  = (const int*)d_in[10];

    int N = in_sizes[3];
    int T = in_sizes[0];                 // N*L*H*D
    int L = T / (N * NHEAD * DIM);

    float* ws   = (float*)d_ws;
    float* Kf   = ws;                    // T floats
    float* Fm   = ws + T;                // N*9
    float* KV   = Fm + (size_t)N * 9;    // N*H*D*D
    float* Ksum = KV + (size_t)N * NHEAD * DIM * DIM;  // N*H*D

    float* outp = (float*)d_out;

    int n4 = T / 4;
    featmap_k<<<(n4 + 255) / 256, 256, 0, stream>>>((const float4*)Kr, (float4*)Kf, n4);
    precompute_F<<<1, 64, 0, stream>>>(K0, K1, R, t, scl, Fm, N);

    int waves = N * L;
    solved_attn<<<(waves + 3) / 4, 256, 0, stream>>>(Qr, Kf, Vr, flag, Fm, outp, h0c, w0c, N, L);

    kv_reduce<<<N * NHEAD, 256, 0, stream>>>(Kf, Vr, flag, KV, Ksum, N, L);

    long long tot = (long long)N * L * NHEAD * DIM;
    unsolved_out<<<(int)((tot + 255) / 256), 256, 0, stream>>>(Qr, KV, Ksum, flag, outp, N, L);
}

// Round 2
// 195.190 us; speedup vs baseline: 1.7926x; 1.7926x over previous
//
#include <hip/hip_runtime.h>
#include <math.h>

#define NHEAD 8
#define DIM   16
#define EPSF  1e-6f
#define KVCH  8          // L-chunks for kv partial reduction

// ---- solved_sample flag decode, robust to int32 / float32 / byte-bool marshalling.
__device__ __forceinline__ bool solved_flag(const void* p, int i) {
    const unsigned int* u = (const unsigned int*)p;
    unsigned int v0 = u[0];
    if (v0 <= 1u)             return u[i] != 0u;                   // int32 0/1
    if (v0 == 0x3F800000u)    return ((const float*)p)[i] != 0.0f; // float32
    return ((const unsigned char*)p)[i] != 0;                      // 1-byte bools
}

__device__ __forceinline__ float fm(float x) {           // elu(x)+1
    return x > 0.f ? x + 1.f : expf(x);
}

// ---- 3x3 inverse in double
__device__ void inv3d(const double* M, double* inv) {
    double det = M[0]*(M[4]*M[8]-M[5]*M[7]) - M[1]*(M[3]*M[8]-M[5]*M[6]) + M[2]*(M[3]*M[7]-M[4]*M[6]);
    double id = 1.0 / det;
    inv[0] =  (M[4]*M[8]-M[5]*M[7])*id;
    inv[1] = -(M[1]*M[8]-M[2]*M[7])*id;
    inv[2] =  (M[1]*M[5]-M[2]*M[4])*id;
    inv[3] = -(M[3]*M[8]-M[5]*M[6])*id;
    inv[4] =  (M[0]*M[8]-M[2]*M[6])*id;
    inv[5] = -(M[0]*M[5]-M[2]*M[3])*id;
    inv[6] =  (M[3]*M[7]-M[4]*M[6])*id;
    inv[7] = -(M[0]*M[7]-M[1]*M[6])*id;
    inv[8] =  (M[0]*M[4]-M[1]*M[3])*id;
}

__device__ void compute_F_one(const float* K0, const float* K1, const float* R,
                              const float* t, float invs, float* Fout, int n) {
    double A[9], B[9];
    for (int i = 0; i < 9; ++i) {
        float a = K0[n*9 + i], b = K1[n*9 + i];
        if (i < 6) { a *= invs; b *= invs; }   // rows 0,1 scaled
        A[i] = (double)a; B[i] = (double)b;
    }
    double iA[9], iB[9];
    inv3d(A, iA); inv3d(B, iB);
    double tx = t[n*3+0], ty = t[n*3+1], tz = t[n*3+2];
    double S[9] = {0.0,-tz,ty, tz,0.0,-tx, -ty,tx,0.0};
    double E[9], M[9];
    for (int i = 0; i < 3; ++i)
        for (int j = 0; j < 3; ++j) {
            double s = 0.0;
            for (int k = 0; k < 3; ++k) s += S[i*3+k] * (double)R[n*9 + k*3 + j];
            E[i*3+j] = s;
        }
    for (int i = 0; i < 3; ++i)
        for (int j = 0; j < 3; ++j) {
            double s = 0.0;
            for (int k = 0; k < 3; ++k) s += E[i*3+k] * iA[k*3+j];
            M[i*3+j] = s;
        }
    for (int i = 0; i < 3; ++i)
        for (int j = 0; j < 3; ++j) {
            double s = 0.0;
            for (int k = 0; k < 3; ++k) s += iB[k*3+i] * M[k*3+j];
            Fout[n*9 + i*3 + j] = (float)s;
        }
}

// ---- launch 1: feature-map K, zero KV/Ksum partials, compute F (block 0)
__global__ void prep(const float4* __restrict__ in, float4* __restrict__ Kf4, int n4,
                     float* __restrict__ zbuf, int nz,
                     const float* __restrict__ K0, const float* __restrict__ K1,
                     const float* __restrict__ R,  const float* __restrict__ t,
                     const int* __restrict__ scale_p, float* __restrict__ Fout, int N) {
    int i = blockIdx.x * blockDim.x + threadIdx.x;
    if (i < n4) {
        float4 x = in[i];
        x.x = fm(x.x); x.y = fm(x.y); x.z = fm(x.z); x.w = fm(x.w);
        Kf4[i] = x;
    }
    if (i < nz) zbuf[i] = 0.f;
    if (blockIdx.x == 0 && threadIdx.x < (unsigned)N) {
        float invs = 1.0f / (float)(*scale_p);
        compute_F_one(K0, K1, R, t, invs, Fout, threadIdx.x);
    }
}

// ---- launch 2: partial KV / Ksum for unsolved samples (direct global reads, atomics)
__launch_bounds__(256)
__global__ void kv_part(const float* __restrict__ Kf, const float* __restrict__ Vr,
                        const void* __restrict__ flags,
                        float* __restrict__ KV, float* __restrict__ Ksum, int N, int L) {
    int bid = blockIdx.x;
    int chunk = bid & (KVCH - 1);
    int h = (bid >> 3) & 7;
    int n = bid >> 6;
    if (n >= N || solved_flag(flags, n)) return;
    int t = threadIdx.x;
    int d = t >> 4, v = t & 15;
    int rowsPer = (L + KVCH - 1) / KVCH;
    int r0 = chunk * rowsPer;
    int r1 = min(r0 + rowsPer, L);
    const float* Kb = Kf + (size_t)n * L * (NHEAD * DIM) + h * DIM;
    const float* Vb = Vr + (size_t)n * L * (NHEAD * DIM) + h * DIM;
    float acc = 0.f, ks = 0.f;
    #pragma unroll 4
    for (int s = r0; s < r1; ++s) {
        float kd = Kb[(size_t)s * (NHEAD * DIM) + d];
        float vv = Vb[(size_t)s * (NHEAD * DIM) + v];
        acc += kd * vv;
        ks  += kd;
    }
    atomicAdd(&KV[(((size_t)n * NHEAD + h) * DIM + d) * DIM + v], acc);
    if (v == 0) atomicAdd(&Ksum[((size_t)n * NHEAD + h) * DIM + d], ks);
}

// ---- launch 3: fused solved-attention + unsolved epilogue
__launch_bounds__(256)
__global__ void mega(const float* __restrict__ Qr, const float* __restrict__ Kf,
                     const float* __restrict__ Vr, const void* __restrict__ flags,
                     const float* __restrict__ F,
                     const float* __restrict__ KV, const float* __restrict__ Ksum,
                     float* __restrict__ outp,
                     const int* __restrict__ h0c_p, const int* __restrict__ w0c_p,
                     int N, int L, int Bs) {
    if ((int)blockIdx.x < Bs) {
        // ---------------- solved path: one wave per query ----------------
        int wid = (blockIdx.x << 2) | (threadIdx.x >> 6);
        wid = __builtin_amdgcn_readfirstlane(wid);
        int lane = threadIdx.x & 63;
        int n = wid / L;
        if (n >= N) return;
        if (!solved_flag(flags, n)) return;
        int s = wid - n * L;
        int W  = *w0c_p;
        int Hc = *h0c_p;
        float px = (float)(s % W);
        float py = (float)(s / W);

        const float* Fn = F + n * 9;
        float a = Fn[0]*px + Fn[1]*py + Fn[2];
        float b = Fn[3]*px + Fn[4]*py + Fn[5];
        float c = Fn[6]*px + Fn[7]*py + Fn[8];
        float nrm = sqrtf(a*a + b*b);
        float mdiv = fmaxf(nrm, 1e-12f);
        a /= mdiv; b /= mdiv; c /= mdiv;
        bool mode = fabsf(b) >= fabsf(a);

        float slope, inter;
        int outerN, innerMax, sI, sO;
        if (mode) {
            float bs = (fabsf(b) < 1e-12f) ? 1e-12f : b;
            slope = -a / bs; inter = -c / bs;
            outerN = W; innerMax = Hc; sI = W; sO = 1;
        } else {
            float as = (fabsf(a) < 1e-12f) ? 1e-12f : a;
            slope = -b / as; inter = -c / as;
            outerN = Hc; innerMax = W; sI = 1; sO = W;
        }

        int c8 = lane >> 3;   // candidate sub-index 0..7
        int h  = lane & 7;    // head

        // Q fragment (feature-mapped) for head h — 16 floats in registers
        const float4* q4 = (const float4*)(Qr + (size_t)wid * (NHEAD * DIM) + h * DIM);
        float q[16];
        {
            float4 a0 = q4[0], a1 = q4[1], a2 = q4[2], a3 = q4[3];
            q[0]=fm(a0.x); q[1]=fm(a0.y); q[2]=fm(a0.z); q[3]=fm(a0.w);
            q[4]=fm(a1.x); q[5]=fm(a1.y); q[6]=fm(a1.z); q[7]=fm(a1.w);
            q[8]=fm(a2.x); q[9]=fm(a2.y); q[10]=fm(a2.z); q[11]=fm(a2.w);
            q[12]=fm(a3.x); q[13]=fm(a3.y); q[14]=fm(a3.z); q[15]=fm(a3.w);
        }

        const float* Kb = Kf + (size_t)n * L * (NHEAD * DIM);
        const float* Vb = Vr + (size_t)n * L * (NHEAD * DIM);

        float acc[16];
        #pragma unroll
        for (int i = 0; i < 16; ++i) acc[i] = 0.f;
        float den = 0.f;

        int totalC = outerN * 3;
        int groups = (totalC + 7) >> 3;
        const float hw = 1.5f;

        for (int g = 0; g < groups; ++g) {
            int m = (g << 3) + c8;          // this lane's candidate index
            int o = m / 3;
            int j = m - o * 3;
            float cc = slope * (float)o + inter;
            float lo = cc - hw, hi = cc + hw;
            int ii = (int)floorf(lo) + 1 + j;
            float fi = (float)ii;
            bool valid = (m < totalC) && (ii >= 0) && (ii < innerMax)
                         && (fi > lo) && (fi < hi);
            int s2 = ii * sI + o * sO;
            valid = valid && (s2 != 0);     // reference's gather drops index 0
            int s2c = valid ? s2 : 0;
            int idx = (s2c << 7) + (h << 4);
            const float4* kr = (const float4*)(Kb + idx);
            const float4* vr = (const float4*)(Vb + idx);
            float4 k0 = kr[0], k1 = kr[1], k2 = kr[2], k3 = kr[3];
            float4 w0 = vr[0], w1 = vr[1], w2 = vr[2], w3 = vr[3];
            float p0 = q[0]*k0.x + q[1]*k0.y + q[2]*k0.z + q[3]*k0.w;
            float p1 = q[4]*k1.x + q[5]*k1.y + q[6]*k1.z + q[7]*k1.w;
            float p2 = q[8]*k2.x + q[9]*k2.y + q[10]*k2.z + q[11]*k2.w;
            float p3 = q[12]*k3.x + q[13]*k3.y + q[14]*k3.z + q[15]*k3.w;
            float sc = (p0 + p1) + (p2 + p3);
            sc = valid ? sc : 0.f;
            den += sc;
            acc[0]  += sc * w0.x; acc[1]  += sc * w0.y; acc[2]  += sc * w0.z; acc[3]  += sc * w0.w;
            acc[4]  += sc * w1.x; acc[5]  += sc * w1.y; acc[6]  += sc * w1.z; acc[7]  += sc * w1.w;
            acc[8]  += sc * w2.x; acc[9]  += sc * w2.y; acc[10] += sc * w2.z; acc[11] += sc * w2.w;
            acc[12] += sc * w3.x; acc[13] += sc * w3.y; acc[14] += sc * w3.z; acc[15] += sc * w3.w;
        }

        // reduce across the 8 candidate-lanes of each head (lanes h, h+8, ..., h+56)
        #pragma unroll
        for (int off = 8; off < 64; off <<= 1) {
            den += __shfl_xor(den, off);
            #pragma unroll
            for (int i = 0; i < 16; ++i) acc[i] += __shfl_xor(acc[i], off);
        }

        if (c8 == 0) {
            float r = 1.0f / (den + EPSF);
            float4* orow = (float4*)(outp + (size_t)wid * (NHEAD * DIM) + h * DIM);
            orow[0] = make_float4(acc[0]*r,  acc[1]*r,  acc[2]*r,  acc[3]*r);
            orow[1] = make_float4(acc[4]*r,  acc[5]*r,  acc[6]*r,  acc[7]*r);
            orow[2] = make_float4(acc[8]*r,  acc[9]*r,  acc[10]*r, acc[11]*r);
            orow[3] = make_float4(acc[12]*r, acc[13]*r, acc[14]*r, acc[15]*r);
        }
    } else {
        // ---------------- unsolved epilogue: out = Q.KV / (Q.Ksum + eps) ----------------
        long long idx = (long long)(blockIdx.x - Bs) * blockDim.x + threadIdx.x;
        long long tot = (long long)N * L * NHEAD * DIM;
        if (idx >= tot) return;
        int v = (int)(idx & 15);
        int h = (int)((idx >> 4) & 7);
        long long ns = idx >> 7;
        int n = (int)(ns / L);
        if (solved_flag(flags, n)) return;
        const float* qrow = Qr + (idx & ~(long long)15);
        const float* kv = KV   + ((size_t)n * NHEAD + h) * DIM * DIM;
        const float* kd = Ksum + ((size_t)n * NHEAD + h) * DIM;
        float num = 0.f, den = 0.f;
        #pragma unroll
        for (int d = 0; d < 16; ++d) {
            float qd = fm(qrow[d]);
            num += qd * kv[d * DIM + v];
            den += qd * kd[d];
        }
        outp[idx] = num / (den + EPSF);
    }
}

extern "C" void kernel_launch(void* const* d_in, const int* in_sizes, int n_in,
                              void* d_out, int out_size, void* d_ws, size_t ws_size,
                              hipStream_t stream) {
    const float* Qr   = (const float*)d_in[0];
    const float* Kr   = (const float*)d_in[1];
    const float* Vr   = (const float*)d_in[2];
    const void*  flag = d_in[3];
    const float* K0   = (const float*)d_in[4];
    const float* K1   = (const float*)d_in[5];
    const float* R    = (const float*)d_in[6];
    const float* t    = (const float*)d_in[7];
    const int*   h0c  = (const int*)d_in[8];
    const int*   w0c  = (const int*)d_in[9];
    const int*   scl  = (const int*)d_in[10];

    int N = in_sizes[3];
    int T = in_sizes[0];                 // N*L*H*D
    int L = T / (N * NHEAD * DIM);

    float* ws   = (float*)d_ws;
    float* Kf   = ws;                                   // T floats
    float* Fm   = Kf + T;                               // N*9
    float* KV   = Fm + (size_t)N * 9;                   // N*H*D*D
    float* Ksum = KV + (size_t)N * NHEAD * DIM * DIM;   // N*H*D
    int nz = N * NHEAD * DIM * DIM + N * NHEAD * DIM;   // KV + Ksum contiguous

    float* outp = (float*)d_out;

    int n4 = T / 4;
    int prep_blocks = (n4 + 255) / 256;
    prep<<<prep_blocks, 256, 0, stream>>>((const float4*)Kr, (float4*)Kf, n4,
                                          KV, nz, K0, K1, R, t, scl, Fm, N);

    kv_part<<<N * NHEAD * KVCH, 256, 0, stream>>>(Kf, Vr, flag, KV, Ksum, N, L);

    int Bs = (N * L + 3) / 4;                           // solved blocks (4 waves each)
    long long tot = (long long)N * L * NHEAD * DIM;
    int Bu = (int)((tot + 255) / 256);                  // unsolved blocks
    mega<<<Bs + Bu, 256, 0, stream>>>(Qr, Kf, Vr, flag, Fm, KV, Ksum, outp,
                                      h0c, w0c, N, L, Bs);
}

// Round 3
// 173.331 us; speedup vs baseline: 2.0186x; 1.1261x over previous
//
#include <hip/hip_runtime.h>
#include <math.h>

#define NHEAD 8
#define DIM   16
#define EPSF  1e-6f
#define KVCH  8          // L-chunks for kv partial reduction

typedef _Float16 half2_t __attribute__((ext_vector_type(2)));
typedef _Float16 half4_t __attribute__((ext_vector_type(4)));
typedef _Float16 half8_t __attribute__((ext_vector_type(8)));

#if defined(__has_builtin)
#if __has_builtin(__builtin_amdgcn_fdot2)
#define HAVE_FDOT2 1
#endif
#endif

__device__ __forceinline__ float dot2(half2_t a, half2_t b, float c) {
#ifdef HAVE_FDOT2
    return __builtin_amdgcn_fdot2(a, b, c, false);
#else
    return c + (float)a.x * (float)b.x + (float)a.y * (float)b.y;
#endif
}

// ---- solved_sample flag decode, robust to int32 / float32 / byte-bool marshalling.
__device__ __forceinline__ bool solved_flag(const void* p, int i) {
    const unsigned int* u = (const unsigned int*)p;
    unsigned int v0 = u[0];
    if (v0 <= 1u)             return u[i] != 0u;                   // int32 0/1
    if (v0 == 0x3F800000u)    return ((const float*)p)[i] != 0.0f; // float32
    return ((const unsigned char*)p)[i] != 0;                      // 1-byte bools
}

__device__ __forceinline__ float fm(float x) {           // elu(x)+1
    return x > 0.f ? x + 1.f : expf(x);
}

// ---- 3x3 inverse in double
__device__ void inv3d(const double* M, double* inv) {
    double det = M[0]*(M[4]*M[8]-M[5]*M[7]) - M[1]*(M[3]*M[8]-M[5]*M[6]) + M[2]*(M[3]*M[7]-M[4]*M[6]);
    double id = 1.0 / det;
    inv[0] =  (M[4]*M[8]-M[5]*M[7])*id;
    inv[1] = -(M[1]*M[8]-M[2]*M[7])*id;
    inv[2] =  (M[1]*M[5]-M[2]*M[4])*id;
    inv[3] = -(M[3]*M[8]-M[5]*M[6])*id;
    inv[4] =  (M[0]*M[8]-M[2]*M[6])*id;
    inv[5] = -(M[0]*M[5]-M[2]*M[3])*id;
    inv[6] =  (M[3]*M[7]-M[4]*M[6])*id;
    inv[7] = -(M[0]*M[7]-M[1]*M[6])*id;
    inv[8] =  (M[0]*M[4]-M[1]*M[3])*id;
}

__device__ void compute_F_one(const float* K0, const float* K1, const float* R,
                              const float* t, float invs, float* Fout, int n) {
    double A[9], B[9];
    for (int i = 0; i < 9; ++i) {
        float a = K0[n*9 + i], b = K1[n*9 + i];
        if (i < 6) { a *= invs; b *= invs; }   // rows 0,1 scaled
        A[i] = (double)a; B[i] = (double)b;
    }
    double iA[9], iB[9];
    inv3d(A, iA); inv3d(B, iB);
    double tx = t[n*3+0], ty = t[n*3+1], tz = t[n*3+2];
    double S[9] = {0.0,-tz,ty, tz,0.0,-tx, -ty,tx,0.0};
    double E[9], M[9];
    for (int i = 0; i < 3; ++i)
        for (int j = 0; j < 3; ++j) {
            double s = 0.0;
            for (int k = 0; k < 3; ++k) s += S[i*3+k] * (double)R[n*9 + k*3 + j];
            E[i*3+j] = s;
        }
    for (int i = 0; i < 3; ++i)
        for (int j = 0; j < 3; ++j) {
            double s = 0.0;
            for (int k = 0; k < 3; ++k) s += E[i*3+k] * iA[k*3+j];
            M[i*3+j] = s;
        }
    for (int i = 0; i < 3; ++i)
        for (int j = 0; j < 3; ++j) {
            double s = 0.0;
            for (int k = 0; k < 3; ++k) s += iB[k*3+i] * M[k*3+j];
            Fout[n*9 + i*3 + j] = (float)s;
        }
}

// ---- kernel 1: role-split blocks.
//   blocks [0, PB):      featmap K -> fp16 Kh, convert V -> fp16 Vh; block 0 also computes F
//   blocks [PB, PB+KB):  KV/Ksum chunk-partials for unsolved samples (raw fp32 K/V, fm inline)
__launch_bounds__(256)
__global__ void prep_kv(const float4* __restrict__ Kr4, const float4* __restrict__ Vr4,
                        _Float16* __restrict__ Kh, _Float16* __restrict__ Vh, int n4,
                        const float* __restrict__ Kr, const float* __restrict__ Vr,
                        const void* __restrict__ flags,
                        float* __restrict__ KVp, float* __restrict__ Ksp,
                        const float* __restrict__ K0, const float* __restrict__ K1,
                        const float* __restrict__ R,  const float* __restrict__ t,
                        const int* __restrict__ scale_p, float* __restrict__ Fout,
                        int N, int L, int PB) {
    if ((int)blockIdx.x < PB) {
        int i = blockIdx.x * 256 + threadIdx.x;
        if (i < n4) {
            float4 k = Kr4[i];
            half4_t kh = { (_Float16)fm(k.x), (_Float16)fm(k.y), (_Float16)fm(k.z), (_Float16)fm(k.w) };
            ((half4_t*)Kh)[i] = kh;
            float4 v = Vr4[i];
            half4_t vh = { (_Float16)v.x, (_Float16)v.y, (_Float16)v.z, (_Float16)v.w };
            ((half4_t*)Vh)[i] = vh;
        }
        if (blockIdx.x == 0 && threadIdx.x < (unsigned)N) {
            float invs = 1.0f / (float)(*scale_p);
            compute_F_one(K0, K1, R, t, invs, Fout, threadIdx.x);
        }
    } else {
        int kb = blockIdx.x - PB;          // 0 .. N*NHEAD*KVCH-1
        int chunk = kb & (KVCH - 1);
        int h = (kb >> 3) & 7;
        int n = kb >> 6;
        if (n >= N || solved_flag(flags, n)) return;
        int tdx = threadIdx.x;
        int d = tdx >> 4, v = tdx & 15;
        int rowsPer = (L + KVCH - 1) / KVCH;
        int r0 = chunk * rowsPer;
        int r1 = min(r0 + rowsPer, L);
        const float* Kb = Kr + (size_t)n * L * (NHEAD * DIM) + h * DIM;
        const float* Vb = Vr + (size_t)n * L * (NHEAD * DIM) + h * DIM;
        float acc = 0.f, ks = 0.f;
        #pragma unroll 8
        for (int s = r0; s < r1; ++s) {
            float kd = fm(Kb[(size_t)s * (NHEAD * DIM) + d]);
            float vv = Vb[(size_t)s * (NHEAD * DIM) + v];
            acc += kd * vv;
            ks  += kd;
        }
        KVp[(((size_t)chunk * N + n) * NHEAD + h) * 256 + (d << 4) + v] = acc;
        if (v == 0) Ksp[(((size_t)chunk * N + n) * NHEAD + h) * 16 + d] = ks;
    }
}

// ---- kernel 2: fused solved-attention (fp16 gather) + unsolved epilogue
__launch_bounds__(256)
__global__ void mega(const float* __restrict__ Qr,
                     const _Float16* __restrict__ Kh, const _Float16* __restrict__ Vh,
                     const void* __restrict__ flags,  const float* __restrict__ F,
                     const float* __restrict__ KVp,   const float* __restrict__ Ksp,
                     float* __restrict__ outp,
                     const int* __restrict__ h0c_p, const int* __restrict__ w0c_p,
                     int N, int L, int Bs) {
    if ((int)blockIdx.x < Bs) {
        // ---------------- solved path: one wave per query ----------------
        int wid = (blockIdx.x << 2) | (threadIdx.x >> 6);
        wid = __builtin_amdgcn_readfirstlane(wid);
        int lane = threadIdx.x & 63;
        int n = wid / L;
        if (n >= N) return;
        if (!solved_flag(flags, n)) return;
        int s = wid - n * L;
        int W  = *w0c_p;
        int Hc = *h0c_p;
        float px = (float)(s % W);
        float py = (float)(s / W);

        const float* Fn = F + n * 9;
        float a = Fn[0]*px + Fn[1]*py + Fn[2];
        float b = Fn[3]*px + Fn[4]*py + Fn[5];
        float c = Fn[6]*px + Fn[7]*py + Fn[8];
        float nrm = sqrtf(a*a + b*b);
        float mdiv = fmaxf(nrm, 1e-12f);
        a /= mdiv; b /= mdiv; c /= mdiv;
        bool mode = fabsf(b) >= fabsf(a);

        float slope, inter;
        int outerN, innerMax, sI, sO;
        if (mode) {
            float bs = (fabsf(b) < 1e-12f) ? 1e-12f : b;
            slope = -a / bs; inter = -c / bs;
            outerN = W; innerMax = Hc; sI = W; sO = 1;
        } else {
            float as = (fabsf(a) < 1e-12f) ? 1e-12f : a;
            slope = -b / as; inter = -c / as;
            outerN = Hc; innerMax = W; sI = 1; sO = W;
        }

        int c8 = lane >> 3;   // candidate sub-index 0..7
        int h  = lane & 7;    // head

        // Q fragment -> fp16 pairs for fdot2
        const float4* q4 = (const float4*)(Qr + (size_t)wid * (NHEAD * DIM) + h * DIM);
        half2_t q2[8];
        {
            float4 a0 = q4[0], a1 = q4[1], a2 = q4[2], a3 = q4[3];
            q2[0] = (half2_t){ (_Float16)fm(a0.x), (_Float16)fm(a0.y) };
            q2[1] = (half2_t){ (_Float16)fm(a0.z), (_Float16)fm(a0.w) };
            q2[2] = (half2_t){ (_Float16)fm(a1.x), (_Float16)fm(a1.y) };
            q2[3] = (half2_t){ (_Float16)fm(a1.z), (_Float16)fm(a1.w) };
            q2[4] = (half2_t){ (_Float16)fm(a2.x), (_Float16)fm(a2.y) };
            q2[5] = (half2_t){ (_Float16)fm(a2.z), (_Float16)fm(a2.w) };
            q2[6] = (half2_t){ (_Float16)fm(a3.x), (_Float16)fm(a3.y) };
            q2[7] = (half2_t){ (_Float16)fm(a3.z), (_Float16)fm(a3.w) };
        }

        const _Float16* Kb = Kh + (size_t)n * L * (NHEAD * DIM);
        const _Float16* Vb = Vh + (size_t)n * L * (NHEAD * DIM);

        half2_t acc2[8];
        #pragma unroll
        for (int i = 0; i < 8; ++i) acc2[i] = (half2_t){ (_Float16)0.f, (_Float16)0.f };
        float den = 0.f;

        int totalC = outerN * 3;
        int groups = (totalC + 7) >> 3;
        const float hw = 1.5f;

        #pragma unroll 2
        for (int g = 0; g < groups; ++g) {
            int m = (g << 3) + c8;
            int o = (int)((unsigned)m / 3u);
            int j = m - o * 3;
            float cc = fmaf(slope, (float)o, inter);
            float lo = cc - hw, hi = cc + hw;
            int ii = (int)floorf(lo) + 1 + j;
            float fi = (float)ii;
            bool valid = (m < totalC) && (ii >= 0) && (ii < innerMax)
                         && (fi > lo) && (fi < hi);
            int s2 = ii * sI + o * sO;
            valid = valid && (s2 != 0);     // reference's gather drops index 0
            int idx = ((valid ? s2 : 0) << 7) + (h << 4);   // element offset (halves)
            const half8_t* kr = (const half8_t*)(Kb + idx);
            const half8_t* vr = (const half8_t*)(Vb + idx);
            half8_t k0 = kr[0], k1 = kr[1];
            half8_t v0 = vr[0], v1 = vr[1];
            union H8 { half8_t v; half2_t h[4]; };
            H8 ku0, ku1, vu0, vu1;
            ku0.v = k0; ku1.v = k1; vu0.v = v0; vu1.v = v1;
            float sA = 0.f, sB = 0.f;
            sA = dot2(q2[0], ku0.h[0], sA);
            sB = dot2(q2[1], ku0.h[1], sB);
            sA = dot2(q2[2], ku0.h[2], sA);
            sB = dot2(q2[3], ku0.h[3], sB);
            sA = dot2(q2[4], ku1.h[0], sA);
            sB = dot2(q2[5], ku1.h[1], sB);
            sA = dot2(q2[6], ku1.h[2], sA);
            sB = dot2(q2[7], ku1.h[3], sB);
            float sc = sA + sB;
            sc = valid ? sc : 0.f;
            den += sc;
            _Float16 sch = (_Float16)sc;
            half2_t scv = (half2_t){ sch, sch };
            acc2[0] += scv * vu0.h[0];
            acc2[1] += scv * vu0.h[1];
            acc2[2] += scv * vu0.h[2];
            acc2[3] += scv * vu0.h[3];
            acc2[4] += scv * vu1.h[0];
            acc2[5] += scv * vu1.h[1];
            acc2[6] += scv * vu1.h[2];
            acc2[7] += scv * vu1.h[3];
        }

        // den: full butterfly (all lanes need it)
        den += __shfl_xor(den, 8);
        den += __shfl_xor(den, 16);
        den += __shfl_xor(den, 32);

        // acc: payload-halving butterfly across lanes differing in bits 3,4,5
        bool hi8 = (lane & 8) != 0;
        half2_t t4[4];
        #pragma unroll
        for (int j2 = 0; j2 < 4; ++j2) {
            half2_t send = hi8 ? acc2[j2] : acc2[4 + j2];
            int rr = __shfl_xor(__builtin_bit_cast(int, send), 8);
            half2_t keep = hi8 ? acc2[4 + j2] : acc2[j2];
            t4[j2] = keep + __builtin_bit_cast(half2_t, rr);
        }
        bool hi16 = (lane & 16) != 0;
        half2_t t2[2];
        #pragma unroll
        for (int j2 = 0; j2 < 2; ++j2) {
            half2_t send = hi16 ? t4[j2] : t4[2 + j2];
            int rr = __shfl_xor(__builtin_bit_cast(int, send), 16);
            half2_t keep = hi16 ? t4[2 + j2] : t4[j2];
            t2[j2] = keep + __builtin_bit_cast(half2_t, rr);
        }
        bool hi32 = (lane & 32) != 0;
        half2_t t1;
        {
            half2_t send = hi32 ? t2[0] : t2[1];
            int rr = __shfl_xor(__builtin_bit_cast(int, send), 32);
            half2_t keep = hi32 ? t2[1] : t2[0];
            t1 = keep + __builtin_bit_cast(half2_t, rr);
        }
        int e0 = (hi8 ? 8 : 0) + (hi16 ? 4 : 0) + (hi32 ? 2 : 0);
        float r = 1.0f / (den + EPSF);
        float2 o2 = { (float)t1.x * r, (float)t1.y * r };
        *(float2*)(outp + (size_t)wid * (NHEAD * DIM) + h * DIM + e0) = o2;
    } else {
        // ---------------- unsolved epilogue: out = Q.KV / (Q.Ksum + eps) ----------------
        long long tot2 = (long long)N * L * NHEAD * DIM / 2;
        long long idx2 = (long long)(blockIdx.x - Bs) * 256 + threadIdx.x;
        if (idx2 >= tot2) return;
        int p = (int)(idx2 & 63);
        int h = p >> 3;
        int v = (p & 7) * 2;
        long long ns = idx2 >> 6;
        int n = (int)(ns / L);
        if (solved_flag(flags, n)) return;
        const float* qrow = Qr + ns * (NHEAD * DIM) + h * DIM;
        float num0 = 0.f, num1 = 0.f, den = 0.f;
        #pragma unroll
        for (int d = 0; d < 16; ++d) {
            float qd = fm(qrow[d]);
            #pragma unroll
            for (int cch = 0; cch < KVCH; ++cch) {
                const float2 kv2 = *(const float2*)(KVp + (((size_t)cch * N + n) * NHEAD + h) * 256 + (d << 4) + v);
                num0 += qd * kv2.x;
                num1 += qd * kv2.y;
                den  += qd * Ksp[(((size_t)cch * N + n) * NHEAD + h) * 16 + d] * (1.0f / 16.0f);
            }
        }
        // note: den accumulated Ksum/16 per (d,chunk) pair? -- no: Ksp summed once per d per chunk.
        den *= 16.0f;  // undo the 1/16 (kept symmetric to avoid a second d-loop)
        float rdiv = 1.0f / (den + EPSF);
        size_t ob = ns * (NHEAD * DIM) + h * DIM + v;
        outp[ob]     = num0 * rdiv;
        outp[ob + 1] = num1 * rdiv;
    }
}

extern "C" void kernel_launch(void* const* d_in, const int* in_sizes, int n_in,
                              void* d_out, int out_size, void* d_ws, size_t ws_size,
                              hipStream_t stream) {
    const float* Qr   = (const float*)d_in[0];
    const float* Kr   = (const float*)d_in[1];
    const float* Vr   = (const float*)d_in[2];
    const void*  flag = d_in[3];
    const float* K0   = (const float*)d_in[4];
    const float* K1   = (const float*)d_in[5];
    const float* R    = (const float*)d_in[6];
    const float* t    = (const float*)d_in[7];
    const int*   h0c  = (const int*)d_in[8];
    const int*   w0c  = (const int*)d_in[9];
    const int*   scl  = (const int*)d_in[10];

    int N = in_sizes[3];
    int T = in_sizes[0];                 // N*L*H*D
    int L = T / (N * NHEAD * DIM);

    _Float16* Kh = (_Float16*)d_ws;                       // T halves
    _Float16* Vh = Kh + T;                                // T halves
    float* Fm   = (float*)(Vh + T);                       // N*9
    float* KVp  = Fm + (size_t)N * 9;                     // KVCH*N*H*256
    float* Ksp  = KVp + (size_t)KVCH * N * NHEAD * 256;   // KVCH*N*H*16

    float* outp = (float*)d_out;

    int n4 = T / 4;
    int PB = (n4 + 255) / 256;
    int KB = N * NHEAD * KVCH;
    prep_kv<<<PB + KB, 256, 0, stream>>>((const float4*)Kr, (const float4*)Vr,
                                         Kh, Vh, n4, Kr, Vr, flag, KVp, Ksp,
                                         K0, K1, R, t, scl, Fm, N, L, PB);

    int Bs = (N * L + 3) / 4;                             // solved blocks (4 waves each)
    long long tot2 = (long long)N * L * NHEAD * DIM / 2;
    int Bu = (int)((tot2 + 255) / 256);
    mega<<<Bs + Bu, 256, 0, stream>>>(Qr, Kh, Vh, flag, Fm, KVp, Ksp, outp,
                                      h0c, w0c, N, L, Bs);
}